// Round 4
// baseline (89.119 us; speedup 1.0000x reference)
//
#include <hip/hip_runtime.h>
#include <hip/hip_bf16.h>
#include <stdint.h>

#define NROWS 100000
#define INDIM 512
#define HID 128
#define NCLS 10
#define LEAKY_ALPHA 0.2f

typedef __bf16 bf16x8_t __attribute__((ext_vector_type(8)));
typedef __bf16 bf16x4_t __attribute__((ext_vector_type(4)));
typedef float f32x4_t __attribute__((ext_vector_type(4)));
typedef unsigned short ushort8_t __attribute__((ext_vector_type(8)));

union Frag {
    bf16x8_t v8;
    bf16x4_t v4[2];
    unsigned short u[8];
};

__device__ __forceinline__ unsigned short f2bf(float x) {
    union { __hip_bfloat16 b; unsigned short u; } cv;
    cv.b = __float2bfloat16(x);
    return cv.u;
}

// ---------------- prep: Qb[c][k] = bf16( (C @ (W_half @ V))[k][c] ) ----------------
// Qb layout [16][1024] bf16, K-major: k<512 -> Q1 (W rows 0..127), k>=512 -> Q2.
// Rows c=10..15 zeroed. Grid: 8 blocks x 256 threads; each block recomputes P
// (tiny) and produces 64 k-rows for both halves.
__global__ __launch_bounds__(256) void k_prep(
    const float* __restrict__ C, const float* __restrict__ W, const float* __restrict__ V,
    unsigned short* __restrict__ Qb) {
    __shared__ float Vl[HID * NCLS];       // 5 KB
    __shared__ float Pl[2][HID][10];       // 10 KB
    __shared__ float Cl[64][132];          // 33.8 KB (padded vs bank conflicts)

    const int tid = threadIdx.x, b = blockIdx.x;
    for (int i = tid; i < HID * NCLS; i += 256) Vl[i] = V[i];
    __syncthreads();

    // P[half][j][c] = dot(W[half*128 + j, :], V[:, c]); one (half,j) per thread
    {
        const int half = tid >> 7, j = tid & 127;
        const float* wr = W + (half * HID + j) * HID;
        float s[NCLS];
#pragma unroll
        for (int c = 0; c < NCLS; ++c) s[c] = 0.f;
        for (int m = 0; m < HID; m += 4) {
            float4 wv = *reinterpret_cast<const float4*>(wr + m);
            float wa[4] = {wv.x, wv.y, wv.z, wv.w};
#pragma unroll
            for (int u = 0; u < 4; ++u)
#pragma unroll
                for (int c = 0; c < NCLS; ++c) s[c] += wa[u] * Vl[(m + u) * NCLS + c];
        }
#pragma unroll
        for (int c = 0; c < NCLS; ++c) Pl[half][j][c] = s[c];
    }
    // stage C rows [k0, k0+64)
    const int k0 = b << 6;
    {
        const int kr = tid >> 2, seg = (tid & 3) << 5;
        const float4* src = reinterpret_cast<const float4*>(C + (k0 + kr) * HID + seg);
#pragma unroll
        for (int j = 0; j < 8; ++j)
            *reinterpret_cast<float4*>(&Cl[kr][seg + 4 * j]) = src[j];
    }
    __syncthreads();

    // Qb entries: 64 k x 10 c x 2 halves = 1280
    for (int e = tid; e < 64 * NCLS * 2; e += 256) {
        const int half = e / (64 * NCLS);
        const int rem = e - half * 64 * NCLS;
        const int kl = rem / NCLS, c = rem - kl * NCLS;
        float s = 0.f;
#pragma unroll 4
        for (int j = 0; j < HID; ++j) s += Cl[kl][j] * Pl[half][j][c];
        Qb[c * 1024 + half * 512 + k0 + kl] = f2bf(s);
    }
    // zero pad rows c = 10..15 for this k-range
    for (int e = tid; e < 6 * 64 * 2; e += 256) {
        const int c = 10 + e / 128;
        const int rem = e & 127;
        const int half = rem >> 6, kl = rem & 63;
        Qb[c * 1024 + half * 512 + k0 + kl] = 0;
    }
}

// ---------------- fused main: logits = leaky(f[n1]@Q1 + f[n2]@Q2), log_softmax ----------------
// BM=64 rows (4 waves x 16), N=16 (10 valid), K=1024 = [f(n1) | f(n2)].
// A gathered f32 -> bf16, chunked K=64, double-buffered LDS; Qb staged once.
__global__ __launch_bounds__(256, 3) void k_main(
    const float* __restrict__ F,            // [NROWS][512] f32
    const unsigned short* __restrict__ Qbg, // [16][1024] bf16
    const int* __restrict__ n1, const int* __restrict__ n2,
    float* __restrict__ Out)                // [NROWS][10] f32
{
    __shared__ unsigned short Qs[16][1032];   // row stride 2064 B (2-way banks)
    __shared__ unsigned short As[2][64][72];  // row stride 144 B  (2-way banks)

    const int tid  = threadIdx.x;
    const int w    = tid >> 6;
    const int lane = tid & 63;
    const int l15  = lane & 15;
    const int kg   = (lane >> 4) << 2;
    const long row0 = (long)blockIdx.x * 64;

    // stage Qb (32 KB, coalesced)
    {
        const int c = tid >> 4, seg = tid & 15;
        const uint4* s = reinterpret_cast<const uint4*>(Qbg + c * 1024 + seg * 64);
        uint4* d = reinterpret_cast<uint4*>(&Qs[c][seg * 64]);
#pragma unroll
        for (int j = 0; j < 8; ++j) d[j] = s[j];
    }

    // gather bases: 4 threads per output row, 64 B (16 f32) each
    const int i = tid >> 2, q = tid & 3;
    long gr = row0 + i;
    if (gr >= NROWS) gr = NROWS - 1;
    const float* b1 = F + (long)n1[gr] * INDIM + q * 16;
    const float* b2 = F + (long)n2[gr] * INDIM + q * 16;
    const int awr = i * 144 + q * 32;   // byte offset of this thread's 32-B slot

    const char* asb = (const char*)&As[0][0][0];
    const char* bsb = (const char*)&Qs[0][0];

    // prologue: stage chunk 0 (k 0..63 from f[n1])
    {
        float4 v[4];
#pragma unroll
        for (int j = 0; j < 4; ++j) v[j] = *reinterpret_cast<const float4*>(b1 + 4 * j);
        ushort8_t lo, hi;
#pragma unroll
        for (int e = 0; e < 4; ++e) {
            lo[e] = f2bf(v[0][e]); lo[4 + e] = f2bf(v[1][e]);
            hi[e] = f2bf(v[2][e]); hi[4 + e] = f2bf(v[3][e]);
        }
        *(ushort8_t*)((char*)asb + awr)      = lo;
        *(ushort8_t*)((char*)asb + awr + 16) = hi;
    }
    __syncthreads();

    f32x4_t acc = {0.f, 0.f, 0.f, 0.f};
    const int afr = (w * 16 + l15) * 144 + kg * 2;   // A frag base (within buffer)
    const int bfr0 = l15 * 2064 + kg * 2;            // B frag base (within Qs)

#pragma unroll
    for (int t = 0; t < 16; ++t) {
        const int cur = t & 1;
        float4 nx[4];
        if (t < 15) {
            // issue next chunk's gathered loads early (consumed after MFMA)
            const int tn = t + 1;
            const float* src = (tn < 8) ? (b1 + tn * 64) : (b2 + (tn - 8) * 64);
#pragma unroll
            for (int j = 0; j < 4; ++j) nx[j] = *reinterpret_cast<const float4*>(src + 4 * j);
        }

        // 2 k-steps of MFMA from current buffer
#pragma unroll
        for (int s = 0; s < 2; ++s) {
            Frag a, bf_;
            const char* ab = asb + cur * 9216 + afr + s * 64;
            a.v4[0]   = *(const bf16x4_t*)(ab);
            a.v4[1]   = *(const bf16x4_t*)(ab + 32);
            const char* bb = bsb + bfr0 + t * 128 + s * 64;
            bf_.v4[0] = *(const bf16x4_t*)(bb);
            bf_.v4[1] = *(const bf16x4_t*)(bb + 32);
            acc = __builtin_amdgcn_mfma_f32_16x16x32_bf16(a.v8, bf_.v8, acc, 0, 0, 0);
        }

        if (t < 15) {
            ushort8_t lo, hi;
#pragma unroll
            for (int e = 0; e < 4; ++e) {
                lo[e] = f2bf(nx[0][e]); lo[4 + e] = f2bf(nx[1][e]);
                hi[e] = f2bf(nx[2][e]); hi[4 + e] = f2bf(nx[3][e]);
            }
            *(ushort8_t*)((char*)asb + (cur ^ 1) * 9216 + awr)      = lo;
            *(ushort8_t*)((char*)asb + (cur ^ 1) * 9216 + awr + 16) = hi;
            __syncthreads();
        }
    }

    // epilogue: leaky + log_softmax; lane col l15 = class, rows rq+r
    const int rq = (lane >> 4) << 2;
#pragma unroll
    for (int r = 0; r < 4; ++r) {
        float x = acc[r];
        x = (x >= 0.f) ? x : LEAKY_ALPHA * x;
        float xm = (l15 < NCLS) ? x : -1e30f;
        float m = xm;
        m = fmaxf(m, __shfl_xor(m, 1));
        m = fmaxf(m, __shfl_xor(m, 2));
        m = fmaxf(m, __shfl_xor(m, 4));
        m = fmaxf(m, __shfl_xor(m, 8));
        float e = (l15 < NCLS) ? __expf(x - m) : 0.f;
        float ssum = e;
        ssum += __shfl_xor(ssum, 1);
        ssum += __shfl_xor(ssum, 2);
        ssum += __shfl_xor(ssum, 4);
        ssum += __shfl_xor(ssum, 8);
        float lse = m + __logf(ssum);
        long grow = row0 + w * 16 + rq + r;
        if (l15 < NCLS && grow < NROWS) Out[grow * NCLS + l15] = x - lse;
    }
}

extern "C" void kernel_launch(void* const* d_in, const int* in_sizes, int n_in,
                              void* d_out, int out_size, void* d_ws, size_t ws_size,
                              hipStream_t stream) {
    const float* features = (const float*)d_in[0];
    const float* C  = (const float*)d_in[1];
    const float* W  = (const float*)d_in[2];
    const float* V  = (const float*)d_in[3];
    const int*   n1 = (const int*)d_in[4];
    const int*   n2 = (const int*)d_in[5];
    float* out = (float*)d_out;

    unsigned short* Qb = (unsigned short*)d_ws;   // 16*1024*2 = 32 KB

    hipLaunchKernelGGL(k_prep, dim3(8), dim3(256), 0, stream, C, W, V, Qb);
    hipLaunchKernelGGL(k_main, dim3((NROWS + 63) / 64), dim3(256), 0, stream,
                       features, Qb, n1, n2, out);
}

// Round 5
// 70.391 us; speedup vs baseline: 1.2661x; 1.2661x over previous
//
#include <hip/hip_runtime.h>
#include <hip/hip_bf16.h>
#include <stdint.h>

#define NROWS 100000
#define INDIM 512
#define HID 128
#define NCLS 10
#define LEAKY_ALPHA 0.2f

typedef __bf16 bf16x8_t __attribute__((ext_vector_type(8)));
typedef __bf16 bf16x4_t __attribute__((ext_vector_type(4)));
typedef float f32x4_t __attribute__((ext_vector_type(4)));
typedef unsigned short ushort8_t __attribute__((ext_vector_type(8)));

union Frag {
    bf16x8_t v8;
    bf16x4_t v4[2];
    unsigned short u[8];
};

__device__ __forceinline__ unsigned short f2bf(float x) {
    union { __hip_bfloat16 b; unsigned short u; } cv;
    cv.b = __float2bfloat16(x);
    return cv.u;
}

// Byte address of element (row r, k element kk) inside an [R x 32] bf16 tile
// image: rows paired into 128-B lines, 16-B units XOR-swizzled by (pair&7).
// Same bank-verified layout as round 3 (b64 frag reads / b128 writes at minimum).
__device__ __forceinline__ int img_addr(int r, int kk) {
    int p = r >> 1;
    int o = ((r & 1) << 6) | (kk << 1);
    return (p << 7) | ((((o >> 4) ^ (p & 7)) << 4) | (o & 15));
}

__device__ __forceinline__ void gload_lds16(const void* g, void* l) {
    __builtin_amdgcn_global_load_lds(
        (const __attribute__((address_space(1))) unsigned int*)g,
        (__attribute__((address_space(3))) unsigned int*)l, 16, 0, 0);
}

// ---------------- prep: Qimg = swizzled tile images of Q = [C@(W1@V) | C@(W2@V)] ----------------
// Q logical [32 cols][512 k] bf16: col n<16 -> Q1 class n (zero for n>=10),
// n>=16 -> Q2 class n-16. Image: k-tile t (k = t*32+kk) at byte t*2048 + img_addr(n, kk).
// 8 blocks, each handles 64 k-rows; each block recomputes P = W@V (tiny).
__global__ __launch_bounds__(256) void k_prep(
    const float* __restrict__ C, const float* __restrict__ W, const float* __restrict__ V,
    unsigned short* __restrict__ Qimg) {
    __shared__ float Vl[HID * NCLS];      // 5 KB
    __shared__ float Pl[2][HID][10];      // 10 KB
    __shared__ float Cl[64][132];         // 33.8 KB

    const int tid = threadIdx.x, b = blockIdx.x;
    for (int i = tid; i < HID * NCLS; i += 256) Vl[i] = V[i];
    __syncthreads();

    // P[half][j][c] = dot(W[half*128 + j, :], V[:, c]); one (half,j) per thread
    {
        const int half = tid >> 7, j = tid & 127;
        const float* wr = W + (half * HID + j) * HID;
        float s[NCLS];
#pragma unroll
        for (int c = 0; c < NCLS; ++c) s[c] = 0.f;
        for (int m = 0; m < HID; m += 4) {
            float4 wv = *reinterpret_cast<const float4*>(wr + m);
            float wa[4] = {wv.x, wv.y, wv.z, wv.w};
#pragma unroll
            for (int u = 0; u < 4; ++u)
#pragma unroll
                for (int c = 0; c < NCLS; ++c) s[c] += wa[u] * Vl[(m + u) * NCLS + c];
        }
#pragma unroll
        for (int c = 0; c < NCLS; ++c) Pl[half][j][c] = s[c];
    }
    // stage C rows [k0, k0+64)
    const int k0 = b << 6;
    {
        const int kr = tid >> 2, seg = (tid & 3) << 5;
        const float4* src = reinterpret_cast<const float4*>(C + (k0 + kr) * HID + seg);
#pragma unroll
        for (int j = 0; j < 8; ++j)
            *reinterpret_cast<float4*>(&Cl[kr][seg + 4 * j]) = src[j];
    }
    __syncthreads();

    // Q entries: 64 k x 32 n
    for (int e = tid; e < 64 * 32; e += 256) {
        const int n = e >> 6, kl = e & 63;
        const int half = n >> 4, c = n & 15;
        float s = 0.f;
        if (c < NCLS) {
#pragma unroll 4
            for (int j = 0; j < HID; ++j) s += Cl[kl][j] * Pl[half][j][c];
        }
        const int k = k0 + kl, t = k >> 5, kk = k & 31;
        *(unsigned short*)((char*)Qimg + t * 2048 + img_addr(n, kk)) = f2bf(s);
    }
}

// ---------------- thin GEMM: g = f @ Q  (sequential stream, N=32) ----------------
// BM=128 rows, BK=32, 4 waves. A reg-staged (f32 -> bf16, swizzled ds_write,
// issue-early/write-late, double-buffered); Q staged ONCE via global_load_lds.
// 48 KB LDS -> 3 blocks/CU.
__global__ __launch_bounds__(256, 3) void k_gemm(
    const float* __restrict__ A,             // [NROWS][512] f32
    const unsigned short* __restrict__ Qimg, // 16 x 2KB swizzled tile images
    float* __restrict__ G)                   // [NROWS][32] f32
{
    __shared__ unsigned short Qs[16384];     // 32 KB: all 16 B-tiles
    __shared__ unsigned short As[2][4096];   // 2 x 8 KB A images

    const int tid  = threadIdx.x;
    const int w    = tid >> 6;
    const int lane = tid & 63;
    const int l15  = lane & 15;
    const int kg   = (lane >> 4) << 2;
    const long row0 = (long)blockIdx.x * 128;

    // stage all of Q once (8 x 1KB per wave, wave-uniform dests)
#pragma unroll
    for (int j = 0; j < 8; ++j) {
        const int off = (j * 4 + w) * 1024;
        gload_lds16((const char*)Qimg + off + lane * 16, (char*)Qs + off);
    }

    // A staging: thread -> (row, 16-elem half); 64 B f32 load per chunk
    const int ar_s = tid >> 1;
    const int kh   = (tid & 1) << 4;
    long gr = row0 + ar_s;
    if (gr >= NROWS) gr = NROWS - 1;
    const float* asrc = A + gr * INDIM + kh;
    const int aw0 = img_addr(ar_s, kh);
    const int aw1 = img_addr(ar_s, kh + 8);

    // fragment read byte-addresses
    int ard0[2], ard1[2], brd0[2], brd1[2];
#pragma unroll
    for (int ii = 0; ii < 2; ++ii) {
        int r = w * 32 + ii * 16 + l15;
        ard0[ii] = img_addr(r, kg);
        ard1[ii] = img_addr(r, kg + 16);
    }
#pragma unroll
    for (int f = 0; f < 2; ++f) {
        brd0[f] = img_addr(f * 16 + l15, kg);
        brd1[f] = img_addr(f * 16 + l15, kg + 16);
    }

    f32x4_t acc[2][2];
#pragma unroll
    for (int i = 0; i < 2; ++i)
#pragma unroll
        for (int f = 0; f < 2; ++f)
#pragma unroll
            for (int r = 0; r < 4; ++r) acc[i][f][r] = 0.f;

    const char* asb = (const char*)&As[0][0];
    const char* bsb = (const char*)&Qs[0];

    // prologue: stage A chunk 0
    {
        float4 v[4];
#pragma unroll
        for (int j = 0; j < 4; ++j) v[j] = *reinterpret_cast<const float4*>(asrc + 4 * j);
        ushort8_t lo, hi;
#pragma unroll
        for (int e = 0; e < 4; ++e) {
            lo[e] = f2bf(v[0][e]); lo[4 + e] = f2bf(v[1][e]);
            hi[e] = f2bf(v[2][e]); hi[4 + e] = f2bf(v[3][e]);
        }
        *(ushort8_t*)((char*)asb + aw0) = lo;
        *(ushort8_t*)((char*)asb + aw1) = hi;
    }
    __syncthreads();   // drains Q global_load_lds too

#pragma unroll
    for (int t = 0; t < 16; ++t) {
        const int cur = t & 1;
        float4 nx[4];
        if (t < 15) {
            // issue next A chunk loads early (consumed after MFMA)
#pragma unroll
            for (int j = 0; j < 4; ++j)
                nx[j] = *reinterpret_cast<const float4*>(asrc + (t + 1) * 32 + 4 * j);
        }

        Frag fa[2], fb[2];
#pragma unroll
        for (int ii = 0; ii < 2; ++ii) {
            fa[ii].v4[0] = *(const bf16x4_t*)(asb + cur * 8192 + ard0[ii]);
            fa[ii].v4[1] = *(const bf16x4_t*)(asb + cur * 8192 + ard1[ii]);
        }
#pragma unroll
        for (int f = 0; f < 2; ++f) {
            fb[f].v4[0] = *(const bf16x4_t*)(bsb + t * 2048 + brd0[f]);
            fb[f].v4[1] = *(const bf16x4_t*)(bsb + t * 2048 + brd1[f]);
        }
#pragma unroll
        for (int ii = 0; ii < 2; ++ii)
#pragma unroll
            for (int f = 0; f < 2; ++f)
                acc[ii][f] = __builtin_amdgcn_mfma_f32_16x16x32_bf16(fa[ii].v8, fb[f].v8, acc[ii][f], 0, 0, 0);

        if (t < 15) {
            ushort8_t lo, hi;
#pragma unroll
            for (int e = 0; e < 4; ++e) {
                lo[e] = f2bf(nx[0][e]); lo[4 + e] = f2bf(nx[1][e]);
                hi[e] = f2bf(nx[2][e]); hi[4 + e] = f2bf(nx[3][e]);
            }
            *(ushort8_t*)((char*)asb + (cur ^ 1) * 8192 + aw0) = lo;
            *(ushort8_t*)((char*)asb + (cur ^ 1) * 8192 + aw1) = hi;
            __syncthreads();
        }
    }

    // epilogue: G[row][l15] = acc[ii][0][r], G[row][16+l15] = acc[ii][1][r]
    const int rq = (lane >> 4) << 2;
#pragma unroll
    for (int ii = 0; ii < 2; ++ii)
#pragma unroll
        for (int r = 0; r < 4; ++r) {
            long grow = row0 + w * 32 + ii * 16 + rq + r;
            if (grow < NROWS) {
                G[grow * 32 + l15]      = acc[ii][0][r];
                G[grow * 32 + 16 + l15] = acc[ii][1][r];
            }
        }
}

// ---------------- epilogue: logits = leaky(g[n1][0:10] + g[n2][16:26]), log_softmax ----------------
__global__ __launch_bounds__(256) void k_epi(
    const float* __restrict__ G,
    const int* __restrict__ n1, const int* __restrict__ n2,
    float* __restrict__ Out) {
    const long i = (long)blockIdx.x * 256 + threadIdx.x;
    if (i >= NROWS) return;
    const float* g1 = G + (long)n1[i] * 32;
    const float* g2 = G + (long)n2[i] * 32 + 16;

    float4 a0 = *(const float4*)(g1);
    float4 a1 = *(const float4*)(g1 + 4);
    float2 a2 = *(const float2*)(g1 + 8);
    float4 b0 = *(const float4*)(g2);
    float4 b1 = *(const float4*)(g2 + 4);
    float2 b2 = *(const float2*)(g2 + 8);

    float x[NCLS] = {a0.x + b0.x, a0.y + b0.y, a0.z + b0.z, a0.w + b0.w,
                     a1.x + b1.x, a1.y + b1.y, a1.z + b1.z, a1.w + b1.w,
                     a2.x + b2.x, a2.y + b2.y};
    float m = -1e30f;
#pragma unroll
    for (int c = 0; c < NCLS; ++c) {
        x[c] = (x[c] >= 0.f) ? x[c] : LEAKY_ALPHA * x[c];
        m = fmaxf(m, x[c]);
    }
    float sum = 0.f;
#pragma unroll
    for (int c = 0; c < NCLS; ++c) sum += __expf(x[c] - m);
    const float lse = m + __logf(sum);
    float* o = Out + i * NCLS;
#pragma unroll
    for (int c = 0; c < NCLS; ++c) o[c] = x[c] - lse;
}

extern "C" void kernel_launch(void* const* d_in, const int* in_sizes, int n_in,
                              void* d_out, int out_size, void* d_ws, size_t ws_size,
                              hipStream_t stream) {
    const float* features = (const float*)d_in[0];
    const float* C  = (const float*)d_in[1];
    const float* W  = (const float*)d_in[2];
    const float* V  = (const float*)d_in[3];
    const int*   n1 = (const int*)d_in[4];
    const int*   n2 = (const int*)d_in[5];
    float* out = (float*)d_out;

    char* ws = (char*)d_ws;
    unsigned short* Qimg = (unsigned short*)ws;            // 32 KB
    float* G = (float*)(ws + 32768);                       // 100000*32*4 = 12.8 MB

    hipLaunchKernelGGL(k_prep, dim3(8), dim3(256), 0, stream, C, W, V, Qimg);
    hipLaunchKernelGGL(k_gemm, dim3((NROWS + 127) / 128), dim3(256), 0, stream,
                       features, Qimg, G);
    hipLaunchKernelGGL(k_epi, dim3((NROWS + 255) / 256), dim3(256), 0, stream,
                       G, n1, n2, out);
}

// Round 6
// 64.403 us; speedup vs baseline: 1.3838x; 1.0930x over previous
//
#include <hip/hip_runtime.h>
#include <hip/hip_bf16.h>
#include <stdint.h>

#define NROWS 100000
#define INDIM 512
#define HID 128
#define NCLS 10
#define LEAKY_ALPHA 0.2f

typedef __bf16 bf16x8_t __attribute__((ext_vector_type(8)));
typedef __bf16 bf16x4_t __attribute__((ext_vector_type(4)));
typedef float f32x4_t __attribute__((ext_vector_type(4)));
typedef unsigned short ushort8_t __attribute__((ext_vector_type(8)));

union Frag {
    bf16x8_t v8;
    bf16x4_t v4[2];
    unsigned short u[8];
};

__device__ __forceinline__ unsigned short f2bf(float x) {
    union { __hip_bfloat16 b; unsigned short u; } cv;
    cv.b = __float2bfloat16(x);
    return cv.u;
}

// Byte address of element (row r, k element kk) inside an [R x 32] bf16 tile
// image: rows paired into 128-B lines, 16-B units XOR-swizzled by (pair&7).
// Bank-verified (round 3): b64 frag reads / b128 writes at conflict minimum.
__device__ __forceinline__ int img_addr(int r, int kk) {
    int p = r >> 1;
    int o = ((r & 1) << 6) | (kk << 1);
    return (p << 7) | ((((o >> 4) ^ (p & 7)) << 4) | (o & 15));
}

__device__ __forceinline__ void gload_lds16(const void* g, void* l) {
    __builtin_amdgcn_global_load_lds(
        (const __attribute__((address_space(1))) unsigned int*)g,
        (__attribute__((address_space(3))) unsigned int*)l, 16, 0, 0);
}

// ---------------- prep: Qimg = swizzled tile images of Q = [C@(W1@V) | C@(W2@V)] ----------------
__global__ __launch_bounds__(256) void k_prep(
    const float* __restrict__ C, const float* __restrict__ W, const float* __restrict__ V,
    unsigned short* __restrict__ Qimg) {
    __shared__ float Vl[HID * NCLS];
    __shared__ float Pl[2][HID][10];
    __shared__ float Cl[64][132];

    const int tid = threadIdx.x, b = blockIdx.x;
    for (int i = tid; i < HID * NCLS; i += 256) Vl[i] = V[i];
    __syncthreads();

    {
        const int half = tid >> 7, j = tid & 127;
        const float* wr = W + (half * HID + j) * HID;
        float s[NCLS];
#pragma unroll
        for (int c = 0; c < NCLS; ++c) s[c] = 0.f;
        for (int m = 0; m < HID; m += 4) {
            float4 wv = *reinterpret_cast<const float4*>(wr + m);
            float wa[4] = {wv.x, wv.y, wv.z, wv.w};
#pragma unroll
            for (int u = 0; u < 4; ++u)
#pragma unroll
                for (int c = 0; c < NCLS; ++c) s[c] += wa[u] * Vl[(m + u) * NCLS + c];
        }
#pragma unroll
        for (int c = 0; c < NCLS; ++c) Pl[half][j][c] = s[c];
    }
    const int k0 = b << 6;
    {
        const int kr = tid >> 2, seg = (tid & 3) << 5;
        const float4* src = reinterpret_cast<const float4*>(C + (k0 + kr) * HID + seg);
#pragma unroll
        for (int j = 0; j < 8; ++j)
            *reinterpret_cast<float4*>(&Cl[kr][seg + 4 * j]) = src[j];
    }
    __syncthreads();

    for (int e = tid; e < 64 * 32; e += 256) {
        const int n = e >> 6, kl = e & 63;
        const int half = n >> 4, c = n & 15;
        float s = 0.f;
        if (c < NCLS) {
#pragma unroll 4
            for (int j = 0; j < HID; ++j) s += Cl[kl][j] * Pl[half][j][c];
        }
        const int k = k0 + kl, t = k >> 5, kk = k & 31;
        *(unsigned short*)((char*)Qimg + t * 2048 + img_addr(n, kk)) = f2bf(s);
    }
}

// ---------------- thin GEMM: g = f @ Q  (sequential stream, N=32, 2-deep prefetch) ----------------
// BM=128, BK=32, 4 waves. A loads issued 3 chunks ahead into a 2-slot register
// queue (converted 2 iters after issue -> ~2 full iterations of HBM-latency
// cover). Q staged once via global_load_lds. 48 KB LDS -> 3 blocks/CU.
__global__ __launch_bounds__(256, 3) void k_gemm(
    const float* __restrict__ A,             // [NROWS][512] f32
    const unsigned short* __restrict__ Qimg, // 16 x 2KB swizzled tile images
    float* __restrict__ G)                   // [NROWS][20] f32 packed
{
    __shared__ unsigned short Qs[16384];     // 32 KB
    __shared__ unsigned short As[2][4096];   // 2 x 8 KB

    const int tid  = threadIdx.x;
    const int w    = tid >> 6;
    const int lane = tid & 63;
    const int l15  = lane & 15;
    const int kg   = (lane >> 4) << 2;
    const long row0 = (long)blockIdx.x * 128;

    // stage all of Q once (wave-uniform dests)
#pragma unroll
    for (int j = 0; j < 8; ++j) {
        const int off = (j * 4 + w) * 1024;
        gload_lds16((const char*)Qimg + off + lane * 16, (char*)Qs + off);
    }

    // A staging: thread -> (row, 16-elem half)
    const int ar_s = tid >> 1;
    const int kh   = (tid & 1) << 4;
    long gr = row0 + ar_s;
    if (gr >= NROWS) gr = NROWS - 1;
    const float* asrc = A + gr * INDIM + kh;
    const int aw0 = img_addr(ar_s, kh);
    const int aw1 = img_addr(ar_s, kh + 8);

    int ard0[2], ard1[2], brd0[2], brd1[2];
#pragma unroll
    for (int ii = 0; ii < 2; ++ii) {
        int r = w * 32 + ii * 16 + l15;
        ard0[ii] = img_addr(r, kg);
        ard1[ii] = img_addr(r, kg + 16);
    }
#pragma unroll
    for (int f = 0; f < 2; ++f) {
        brd0[f] = img_addr(f * 16 + l15, kg);
        brd1[f] = img_addr(f * 16 + l15, kg + 16);
    }

    f32x4_t acc[2][2];
#pragma unroll
    for (int i = 0; i < 2; ++i)
#pragma unroll
        for (int f = 0; f < 2; ++f)
#pragma unroll
            for (int r = 0; r < 4; ++r) acc[i][f][r] = 0.f;

    const char* asb = (const char*)&As[0][0];
    const char* bsb = (const char*)&Qs[0];

    float4 rqA[4], rqB[4];   // even-chunk / odd-chunk register queues

    // prologue: chunk 0 staged directly; chunk 1 -> rqB; chunk 2 -> rqA
    {
        float4 v[4];
#pragma unroll
        for (int j = 0; j < 4; ++j) v[j] = *reinterpret_cast<const float4*>(asrc + 4 * j);
        ushort8_t lo, hi;
#pragma unroll
        for (int e = 0; e < 4; ++e) {
            lo[e] = f2bf(v[0][e]); lo[4 + e] = f2bf(v[1][e]);
            hi[e] = f2bf(v[2][e]); hi[4 + e] = f2bf(v[3][e]);
        }
        *(ushort8_t*)((char*)asb + aw0) = lo;
        *(ushort8_t*)((char*)asb + aw1) = hi;
    }
#pragma unroll
    for (int j = 0; j < 4; ++j) rqB[j] = *reinterpret_cast<const float4*>(asrc + 32 + 4 * j);
#pragma unroll
    for (int j = 0; j < 4; ++j) rqA[j] = *reinterpret_cast<const float4*>(asrc + 64 + 4 * j);
    __syncthreads();   // also drains Q global_load_lds

#pragma unroll
    for (int t = 0; t < 16; ++t) {
        const int cur = t & 1;

        Frag fa[2], fb[2];
#pragma unroll
        for (int ii = 0; ii < 2; ++ii) {
            fa[ii].v4[0] = *(const bf16x4_t*)(asb + cur * 8192 + ard0[ii]);
            fa[ii].v4[1] = *(const bf16x4_t*)(asb + cur * 8192 + ard1[ii]);
        }
#pragma unroll
        for (int f = 0; f < 2; ++f) {
            fb[f].v4[0] = *(const bf16x4_t*)(bsb + t * 2048 + brd0[f]);
            fb[f].v4[1] = *(const bf16x4_t*)(bsb + t * 2048 + brd1[f]);
        }
#pragma unroll
        for (int ii = 0; ii < 2; ++ii)
#pragma unroll
            for (int f = 0; f < 2; ++f)
                acc[ii][f] = __builtin_amdgcn_mfma_f32_16x16x32_bf16(fa[ii].v8, fb[f].v8, acc[ii][f], 0, 0, 0);

        if (t < 15) {
            // convert chunk t+1 from its register slot, write to other buffer
            ushort8_t lo, hi;
            if (((t + 1) & 1) == 1) {
#pragma unroll
                for (int e = 0; e < 4; ++e) {
                    lo[e] = f2bf(rqB[0][e]); lo[4 + e] = f2bf(rqB[1][e]);
                    hi[e] = f2bf(rqB[2][e]); hi[4 + e] = f2bf(rqB[3][e]);
                }
            } else {
#pragma unroll
                for (int e = 0; e < 4; ++e) {
                    lo[e] = f2bf(rqA[0][e]); lo[4 + e] = f2bf(rqA[1][e]);
                    hi[e] = f2bf(rqA[2][e]); hi[4 + e] = f2bf(rqA[3][e]);
                }
            }
            *(ushort8_t*)((char*)asb + (cur ^ 1) * 8192 + aw0) = lo;
            *(ushort8_t*)((char*)asb + (cur ^ 1) * 8192 + aw1) = hi;

            // refill the just-freed slot with chunk t+3 (issued before barrier)
            if (t + 3 <= 15) {
                const float* src = asrc + (t + 3) * 32;
                if (((t + 3) & 1) == 1) {
#pragma unroll
                    for (int j = 0; j < 4; ++j) rqB[j] = *reinterpret_cast<const float4*>(src + 4 * j);
                } else {
#pragma unroll
                    for (int j = 0; j < 4; ++j) rqA[j] = *reinterpret_cast<const float4*>(src + 4 * j);
                }
            }
            __syncthreads();
        }
    }

    // epilogue: packed G rows of 20 f32: [0,10) = f@Q1, [10,20) = f@Q2
    const int rq_ = (lane >> 4) << 2;
#pragma unroll
    for (int ii = 0; ii < 2; ++ii)
#pragma unroll
        for (int r = 0; r < 4; ++r) {
            long grow = row0 + w * 32 + ii * 16 + rq_ + r;
            if (l15 < NCLS && grow < NROWS) {
                G[grow * 20 + l15]        = acc[ii][0][r];
                G[grow * 20 + 10 + l15]   = acc[ii][1][r];
            }
        }
}

// ---------------- epilogue: logits = leaky(g[n1][0:10] + g[n2][10:20]), log_softmax ----------------
__global__ __launch_bounds__(256) void k_epi(
    const float* __restrict__ G,
    const int* __restrict__ n1, const int* __restrict__ n2,
    float* __restrict__ Out) {
    const long i = (long)blockIdx.x * 256 + threadIdx.x;
    if (i >= NROWS) return;
    const float2* g1 = (const float2*)(G + (long)n1[i] * 20);
    const float2* g2 = (const float2*)(G + (long)n2[i] * 20 + 10);

    float x[NCLS];
#pragma unroll
    for (int j = 0; j < 5; ++j) {
        float2 a = g1[j], b = g2[j];
        x[2 * j]     = a.x + b.x;
        x[2 * j + 1] = a.y + b.y;
    }
    float m = -1e30f;
#pragma unroll
    for (int c = 0; c < NCLS; ++c) {
        x[c] = (x[c] >= 0.f) ? x[c] : LEAKY_ALPHA * x[c];
        m = fmaxf(m, x[c]);
    }
    float sum = 0.f;
#pragma unroll
    for (int c = 0; c < NCLS; ++c) sum += __expf(x[c] - m);
    const float lse = m + __logf(sum);
    float2* o = (float2*)(Out + i * NCLS);
#pragma unroll
    for (int j = 0; j < 5; ++j) {
        float2 v = {x[2 * j] - lse, x[2 * j + 1] - lse};
        o[j] = v;
    }
}

extern "C" void kernel_launch(void* const* d_in, const int* in_sizes, int n_in,
                              void* d_out, int out_size, void* d_ws, size_t ws_size,
                              hipStream_t stream) {
    const float* features = (const float*)d_in[0];
    const float* C  = (const float*)d_in[1];
    const float* W  = (const float*)d_in[2];
    const float* V  = (const float*)d_in[3];
    const int*   n1 = (const int*)d_in[4];
    const int*   n2 = (const int*)d_in[5];
    float* out = (float*)d_out;

    char* ws = (char*)d_ws;
    unsigned short* Qimg = (unsigned short*)ws;   // 32 KB
    float* G = (float*)(ws + 32768);              // 100000*20*4 = 8 MB

    hipLaunchKernelGGL(k_prep, dim3(8), dim3(256), 0, stream, C, W, V, Qimg);
    hipLaunchKernelGGL(k_gemm, dim3((NROWS + 127) / 128), dim3(256), 0, stream,
                       features, Qimg, G);
    hipLaunchKernelGGL(k_epi, dim3((NROWS + 255) / 256), dim3(256), 0, stream,
                       G, n1, n2, out);
}